// Round 13
// baseline (537.416 us; speedup 1.0000x reference)
//
#include <hip/hip_runtime.h>
#include <math.h>

#define BB 64
#define TT 1024
#define KK 128
#define START_TAG 126
#define STOP_TAG 127
#define NTH 256      // 4 waves; r = tid>>1 (owned row), h = tid&1 (column half)
#define CS 64        // timesteps of F staged per chunk (32 KB LDS)

typedef float v4f __attribute__((ext_vector_type(4)));

// Raw workgroup barrier WITHOUT the vmcnt(0) drain __syncthreads performs.
// Feat prefetch stays in flight across the whole chunk (validated r7-r12).
__device__ __forceinline__ void step_barrier() {
  asm volatile("s_waitcnt lgkmcnt(0)" ::: "memory");
  __builtin_amdgcn_s_barrier();
  asm volatile("" ::: "memory");
}

// Lane^1 pair exchange via DPP quad_perm [1,0,3,2] — single-level reduce.
__device__ __forceinline__ float pair_add(float x) {
  int y = __builtin_amdgcn_update_dpp(0, __float_as_int(x), 0xB1, 0xF, 0xF, true);
  return x + __int_as_float(y);
}
__device__ __forceinline__ float pair_max(float x) {
  int y = __builtin_amdgcn_update_dpp(0, __float_as_int(x), 0xB1, 0xF, 0xF, true);
  return fmaxf(x, __int_as_float(y));
}

// Forward algorithm, log/exp-free inner chain, lag-1 normalization.
// Pair-split: lane owns row r = tid>>1, cols 64h..64h+63 (64 E floats/lane —
// the proven no-spill budget). Per step: 16 broadcast b128 e-reads (2 addrs/
// read = free 2-way), 32 pk_fma, sum tree, ONE DPP pair-add (vs 2-level quad),
// e' write by h==0 (bank-perfect b32), lag-1 divisor, unconditional log (no
// wave-0 skew at the barrier). Round-12 lesson: bank conflicts and the vmcnt
// drain were fully hidden; the chain is reduce->write->barrier->read latency
// plus 1-wave/SIMD issue stalls — this version shortens exactly those.
__global__ __launch_bounds__(NTH, 1) void crf_forward(
    const float* __restrict__ feats,   // [B,T,K]
    const int*   __restrict__ tags,    // [B,T]
    const int*   __restrict__ lens,    // [B]
    const float* __restrict__ trans,   // [K,K]
    float*       __restrict__ out_pb)  // [B]: forward_score - gold_score
{
  __shared__ __align__(16) float ebuf[2][KK];       // double-buffered e
  __shared__ float sbuf[2];                         // double-buffered divisor
  __shared__ __align__(16) float maxT_lds[KK];
  __shared__ __align__(16) float Fbuf[CS * KK];     // 32 KB: F = exp(feat+maxT)
  __shared__ float wsum[NTH / 64];

  const int tid = threadIdx.x;
  const int b   = blockIdx.x;
  const int r   = tid >> 1;                         // owned row 0..127
  const int h   = tid & 1;                          // column half
  const int L   = lens[b];
  const float* fb = feats + (size_t)b * TT * KK;

  // ---- E half-row in 16 named v4f (64 floats); row max via pair DPP ----
#define EREGS(X) X(0) X(1) X(2) X(3) X(4) X(5) X(6) X(7) \
                 X(8) X(9) X(10) X(11) X(12) X(13) X(14) X(15)
#define DECLE(i) v4f E##i;
  EREGS(DECLE)
  float mT = -INFINITY;
  {
    const v4f* tr = (const v4f*)(trans + (size_t)r * KK + h * 64);
#define LOADE(i) E##i = tr[i];                                          \
    mT = fmaxf(mT, fmaxf(fmaxf(E##i[0], E##i[1]), fmaxf(E##i[2], E##i[3])));
    EREGS(LOADE)
  }
  mT = pair_max(mT);                                // full-row max in both lanes
#define EXPE(i) {                                                       \
    v4f v = E##i;                                                       \
    v[0] = __expf(v[0] - mT); v[1] = __expf(v[1] - mT);                 \
    v[2] = __expf(v[2] - mT); v[3] = __expf(v[3] - mT);                 \
    E##i = v; }
  EREGS(EXPE)
  if (h == 0) maxT_lds[r] = mT;

  // ---- init: e0 = onehot(START), s0 = 1, M0 = feats[b,0,START] ----
  if (tid < KK) ebuf[0][tid] = (tid == START_TAG) ? 1.0f : 0.0f;
  if (tid == 0) sbuf[0] = 1.0f;
  float M = fb[START_TAG];                          // uniform; wave 0's is used

  // ---- prefetch chunk 0 feats (8 x float4/lane, dense 16B stride) ----
  float4 pf[8];
  {
    const float4* s4 = (const float4*)fb;
    #pragma unroll
    for (int i = 0; i < 8; ++i) pf[i] = s4[i * NTH + tid];
  }

  step_barrier();                                   // maxT/ebuf/sbuf visible

  // conversion slice: flat elem (i*NTH+tid)*4+c has j = ((tid&31)*4+c) for all i
  const v4f mTv = *(const v4f*)(maxT_lds + (tid & 31) * 4);

  // ---- chunked main recurrence ----
  int p = 0;
  for (int c = 0; c * CS < L; ++c) {
    // convert prefetched feats -> F = exp(feat + maxT), dense conflict-free writes
    float4* Fb4 = (float4*)Fbuf;
    #pragma unroll
    for (int i = 0; i < 8; ++i) {
      float4 v = pf[i];
      float4 o;
      o.x = __expf(v.x + mTv[0]); o.y = __expf(v.y + mTv[1]);
      o.z = __expf(v.z + mTv[2]); o.w = __expf(v.w + mTv[3]);
      Fb4[i * NTH + tid] = o;
    }
    // prefetch chunk c+1; stays outstanding across all step barriers
    if ((c + 1) * CS < TT) {
      const float4* s4 = (const float4*)(fb + (size_t)(c + 1) * CS * KK);
      #pragma unroll
      for (int i = 0; i < 8; ++i) pf[i] = s4[i * NTH + tid];
    }
    step_barrier();                                 // Fbuf visible

    const int t_end = (L < (c + 1) * CS) ? L : (c + 1) * CS;
    for (int t = (c == 0) ? 1 : c * CS; t < t_end; ++t) {
      // off-chain factors: stale divisor (exact: M += log(sp)), own-row F
      const float sp = sbuf[p];
      const float Fr = Fbuf[(t & (CS - 1)) * KK + r];
      float rr; asm("v_rcp_f32 %0, %1" : "=v"(rr) : "v"(sp));
      const float rF = rr * Fr;

      // dot phase: 16 b128 broadcast reads (2 addrs/wave-read), 32 pk_fma
      const v4f* e4 = (const v4f*)(ebuf[p] + h * 64);
      v4f a0 = {0.f,0.f,0.f,0.f}, a1 = a0, a2 = a0, a3 = a0;
#define DOTE4(i0,i1,i2,i3)                                              \
      a0 += e4[i0] * E##i0;                                             \
      a1 += e4[i1] * E##i1;                                             \
      a2 += e4[i2] * E##i2;                                             \
      a3 += e4[i3] * E##i3;
      DOTE4(0,1,2,3) DOTE4(4,5,6,7) DOTE4(8,9,10,11) DOTE4(12,13,14,15)
      v4f av = (a0 + a1) + (a2 + a3);
      const float half = (av[0] + av[1]) + (av[2] + av[3]);
      const float d = pair_add(half);               // full dot in both pair lanes

      const float ev = d * rF;
      if (h == 0) ebuf[p ^ 1][r] = ev;              // bank-perfect b32 write
      if (tid == 252) sbuf[p ^ 1] = d;              // r=126 h=0: START row, E=1s
      M += __logf(sp);                              // uniform on ALL lanes: no skew
      p ^= 1;
      step_barrier();
    }
  }

  // ---- terminal: fwd = M + log(sum_j e_j), wave 0 ----
  float fwd = 0.f;
  {
    const float* efin = ebuf[p];
    if (tid < 64) {
      float sm = efin[tid] + efin[tid + 64];
      #pragma unroll
      for (int m = 1; m < 64; m <<= 1) sm += __shfl_xor(sm, m, 64);
      fwd = M + __logf(sm);
    }
  }

  // ---- gold score (trans/feats L2-hot; independent gathers) ----
  float gg = 0.f;
  const int* tg = tags + b * TT;
  for (int t = tid; t < TT; t += NTH) {
    if (t < L)     gg += fb[(size_t)t * KK + tg[t]];
    if (t < L - 1) gg += trans[(size_t)tg[t + 1] * KK + tg[t]];
  }
  #pragma unroll
  for (int m = 1; m < 64; m <<= 1) gg += __shfl_xor(gg, m, 64);
  if ((tid & 63) == 0) wsum[tid >> 6] = gg;
  step_barrier();
  if (tid == 0) {
    float gold = 0.f;
    #pragma unroll
    for (int w = 0; w < NTH / 64; ++w) gold += wsum[w];
    out_pb[b] = fwd - gold;
  }
}

__global__ void crf_mean(const float* __restrict__ pb, float* __restrict__ out) {
  int tid = threadIdx.x;  // 64 threads, one wave
  float v = pb[tid];
  #pragma unroll
  for (int m = 1; m < 64; m <<= 1) v += __shfl_xor(v, m, 64);
  if (tid == 0) out[0] = v * (1.0f / 64.0f);
}

extern "C" void kernel_launch(void* const* d_in, const int* in_sizes, int n_in,
                              void* d_out, int out_size, void* d_ws, size_t ws_size,
                              hipStream_t stream) {
  const float* feats = (const float*)d_in[0];
  const int*   tags  = (const int*)d_in[1];
  const int*   lens  = (const int*)d_in[2];
  const float* trans = (const float*)d_in[3];
  float* pb = (float*)d_ws;   // 64 floats of scratch
  crf_forward<<<BB, NTH, 0, stream>>>(feats, tags, lens, trans, pb);
  crf_mean<<<1, 64, 0, stream>>>(pb, (float*)d_out);
}

// Round 19
// 428.947 us; speedup vs baseline: 1.2529x; 1.2529x over previous
//
#include <hip/hip_runtime.h>
#include <math.h>

#define BB 64
#define TT 1024
#define KK 128
#define START_TAG 126
#define STOP_TAG 127
#define NTHREADS 256   // 4 waves; thread: q = tid&3 (k-chunk of 32), g = tid>>2 -> rows 2g,2g+1
#define CS 64          // timesteps of F staged per chunk (32 KB LDS)
#define EP 36          // padded stride (floats) per 32-float e-chunk: q*36 -> disjoint banks

typedef float v2f __attribute__((ext_vector_type(2)));

// Intra-quad reductions via DPP quad_perm (lanes 4g..4g+3 hold k-chunk partials).
// Add tree matches the old cross-wave tree: (q0+q1)+(q2+q3) -> bit-identical sums.
__device__ __forceinline__ float quad_add(float x) {
  int y = __builtin_amdgcn_update_dpp(0, __float_as_int(x), 0xB1, 0xF, 0xF, true); // [1,0,3,2]
  x = x + __int_as_float(y);
  y = __builtin_amdgcn_update_dpp(0, __float_as_int(x), 0x4E, 0xF, 0xF, true);     // [2,3,0,1]
  return x + __int_as_float(y);
}
__device__ __forceinline__ float quad_max(float x) {
  int y = __builtin_amdgcn_update_dpp(0, __float_as_int(x), 0xB1, 0xF, 0xF, true);
  x = fmaxf(x, __int_as_float(y));
  y = __builtin_amdgcn_update_dpp(0, __float_as_int(x), 0x4E, 0xF, 0xF, true);
  return fmaxf(x, __int_as_float(y));
}

// Forward algorithm, log/exp-free inner chain, lag-1 normalization:
//   E[j][k] = exp(T[j][k] - maxT[j])    (registers; rows START get all-1 => d_START = sum_k e_k)
//   F[t][j] = exp(feat[t][j] + maxT[j]) (LDS, staged per 64-step chunk)
//   d_j     = sum_k e_k E[j][k]         (32 MACs/thread, quad DPP reduce -> full d_j in-lane)
//   e'_j    = d_j * F[t][j] * (1/s_prev)   s_prev = d_START from the PREVIOUS step (stale
//             divisor is exact: any positive divisor works as long as M += log(divisor))
//   M      += log(s_prev)               (wave 0 only; consumed only at the end)
// One barrier per step: e double-buffered in LDS (read ebuf[p], write ebuf[p^1]).
// SESSION CHAMPION (r1: crf_forward 363us). Measured-benign: the 4-lane same-
// address e' write (1.25M bank conflicts) and __syncthreads' vmcnt drain (chunk
// prefetch completes in the first ~2 steps of each 64-step chunk) — removing
// either (r12) was within noise. Per-step cost is the serial exchange latency.
__global__ __launch_bounds__(NTHREADS) void crf_forward(
    const float* __restrict__ feats,   // [B,T,K]
    const int*   __restrict__ tags,    // [B,T]
    const int*   __restrict__ lens,    // [B]
    const float* __restrict__ trans,   // [K,K]
    float*       __restrict__ out_pb)  // [B]: forward_score - gold_score
{
  __shared__ float Tld[KK][KK + 1];                 // raw transitions; reused by gold score
  __shared__ __align__(16) float ebuf[2][4 * EP];   // double-buffered e, padded chunk layout
  __shared__ float sbuf[2];                         // double-buffered divisor s
  __shared__ float maxT_lds[KK];
  __shared__ __align__(16) float Fbuf[CS * KK];     // 32 KB: F for current chunk
  __shared__ float wsum[NTHREADS / 64];

  const int tid = threadIdx.x;
  const int b   = blockIdx.x;
  const int q   = tid & 3;                          // k-chunk (32 wide)
  const int g   = tid >> 2;                         // 0..63
  const int r0  = 2 * g;                            // rows r0, r0+1 owned by this thread
  const int L   = lens[b];
  const float* fb = feats + (size_t)b * TT * KK;

  // ---- stage transitions into LDS (vectorized global reads) ----
  for (int i = tid; i < KK * KK / 4; i += NTHREADS) {
    float4 v = ((const float4*)trans)[i];
    int rr = i >> 5, cc = (i & 31) * 4;
    Tld[rr][cc] = v.x; Tld[rr][cc + 1] = v.y; Tld[rr][cc + 2] = v.z; Tld[rr][cc + 3] = v.w;
  }
  __syncthreads();

  // ---- per-thread E row-pair (float2 pairs); row max via quad DPP ----
  float m0 = -INFINITY, m1 = -INFINITY;
  #pragma unroll
  for (int i = 0; i < 32; ++i) {
    m0 = fmaxf(m0, Tld[r0][q * 32 + i]);
    m1 = fmaxf(m1, Tld[r0 + 1][q * 32 + i]);
  }
  m0 = quad_max(m0);
  m1 = quad_max(m1);
  v2f Ea[16], Eb[16];
  #pragma unroll
  for (int i = 0; i < 16; ++i) {
    Ea[i][0] = __expf(Tld[r0][q * 32 + 2 * i]         - m0);
    Ea[i][1] = __expf(Tld[r0][q * 32 + 2 * i + 1]     - m0);
    Eb[i][0] = __expf(Tld[r0 + 1][q * 32 + 2 * i]     - m1);
    Eb[i][1] = __expf(Tld[r0 + 1][q * 32 + 2 * i + 1] - m1);
  }
  if (q == 0) { maxT_lds[r0] = m0; maxT_lds[r0 + 1] = m1; }

  // ---- init: e0 = onehot(START) (padded layout), s0 = 1, M0 = feats[b,0,START] ----
  if (tid < KK)
    ebuf[0][(tid >> 5) * EP + (tid & 31)] = (tid == START_TAG) ? 1.0f : 0.0f;
  if (tid == 0) sbuf[0] = 1.0f;
  float M = fb[START_TAG];                          // redundant across threads; wave 0's is used
  __syncthreads();                                  // maxT_lds + ebuf + sbuf visible

  // per-thread 32-float maxT slice for F conversion (loop-invariant)
  const int j0 = (tid * 32) & (KK - 1);
  float4 mTv[8];
  #pragma unroll
  for (int i = 0; i < 8; ++i) mTv[i] = ((const float4*)maxT_lds)[(j0 >> 2) + i];

  // ---- prefetch chunk 0 feats into registers (32 floats/thread) ----
  float4 pf[8];
  {
    const float4* src = (const float4*)fb;
    #pragma unroll
    for (int i = 0; i < 8; ++i) pf[i] = src[tid * 8 + i];
  }

  // ---- chunked main recurrence ----
  int p = 0;
  for (int c = 0; c * CS < L; ++c) {
    // convert prefetched feats -> F = exp(feat + maxT), write to Fbuf
    float4* Fb4 = (float4*)Fbuf;
    #pragma unroll
    for (int i = 0; i < 8; ++i) {
      float4 v = pf[i], mm = mTv[i];
      float4 o;
      o.x = __expf(v.x + mm.x); o.y = __expf(v.y + mm.y);
      o.z = __expf(v.z + mm.z); o.w = __expf(v.w + mm.w);
      Fb4[tid * 8 + i] = o;
    }
    // issue prefetch for chunk c+1 (drained once at the next barrier's vmcnt(0))
    if ((c + 1) * CS < TT) {
      const float4* src = (const float4*)(fb + (size_t)(c + 1) * CS * KK);
      #pragma unroll
      for (int i = 0; i < 8; ++i) pf[i] = src[tid * 8 + i];
    }
    __syncthreads();                                // Fbuf visible

    const int t_begin = (c == 0) ? 1 : c * CS;
    const int t_end   = (L < (c + 1) * CS) ? L : (c + 1) * CS;
    for (int t = t_begin; t < t_end; ++t) {
      const float* er = ebuf[p];
      float* ew = ebuf[p ^ 1];
      // off-chain: stale divisor, rcp, r*F products ready before d completes
      const float sp = sbuf[p];
      const v2f Fv = *(const v2f*)(Fbuf + (t & (CS - 1)) * KK + r0);
      float rr;
      asm("v_rcp_f32 %0, %1" : "=v"(rr) : "v"(sp));
      const float rF0 = rr * Fv[0];
      const float rF1 = rr * Fv[1];

      // dot phase: 32 pk_fma/thread, e broadcast-read from padded LDS chunk
      const v2f* ep2 = (const v2f*)(er + q * EP);
      v2f a0 = {0.f,0.f}, a1 = {0.f,0.f}, a2 = {0.f,0.f}, a3 = {0.f,0.f};
      v2f b0 = {0.f,0.f}, b1 = {0.f,0.f}, b2 = {0.f,0.f}, b3 = {0.f,0.f};
      #pragma unroll
      for (int i = 0; i < 4; ++i) {
        v2f e0 = ep2[4 * i + 0], e1 = ep2[4 * i + 1];
        v2f e2 = ep2[4 * i + 2], e3 = ep2[4 * i + 3];
        a0 += e0 * Ea[4 * i + 0];
        a1 += e1 * Ea[4 * i + 1];
        a2 += e2 * Ea[4 * i + 2];
        a3 += e3 * Ea[4 * i + 3];
        b0 += e0 * Eb[4 * i + 0];
        b1 += e1 * Eb[4 * i + 1];
        b2 += e2 * Eb[4 * i + 2];
        b3 += e3 * Eb[4 * i + 3];
      }
      v2f as = (a0 + a1) + (a2 + a3);
      v2f bs = (b0 + b1) + (b2 + b3);
      float d0 = quad_add(as[0] + as[1]);           // full d_{r0}  in all 4 lanes
      float d1 = quad_add(bs[0] + bs[1]);           // full d_{r0+1}

      v2f ev; ev[0] = d0 * rF0; ev[1] = d1 * rF1;
      *(v2f*)(ew + (r0 >> 5) * EP + (r0 & 31)) = ev; // 4 lanes same addr, same data: benign
      if (g == 63) sbuf[p ^ 1] = d0;                // row 126 = START: d0 = sum_k e_k
      if (tid < 64) M += __logf(sp);                // off the data chain, wave 0 only
      p ^= 1;
      __syncthreads();
    }
  }

  // ---- terminal: fwd = M + log(sum_k e_k), wave 0 ----
  float fwd = 0.f;
  {
    const float* efin = ebuf[p];
    if (tid < 64) {
      float sm = efin[(tid >> 5) * EP + (tid & 31)]
               + efin[((tid + 64) >> 5) * EP + ((tid + 64) & 31)];
      #pragma unroll
      for (int m = 1; m < 64; m <<= 1) sm += __shfl_xor(sm, m, 64);
      fwd = M + __logf(sm);
    }
  }

  // ---- gold score (all threads; Tld still holds raw transitions) ----
  float gold = 0.f;
  const int* tg = tags + b * TT;
  for (int t = tid; t < TT; t += NTHREADS) {
    if (t < L)     gold += fb[(size_t)t * KK + tg[t]];
    if (t < L - 1) gold += Tld[tg[t + 1]][tg[t]];
  }
  #pragma unroll
  for (int m = 1; m < 64; m <<= 1) gold += __shfl_xor(gold, m, 64);
  if ((tid & 63) == 0) wsum[tid >> 6] = gold;
  __syncthreads();
  if (tid == 0) {
    float gs = 0.f;
    #pragma unroll
    for (int w = 0; w < NTHREADS / 64; ++w) gs += wsum[w];
    out_pb[b] = fwd - gs;
  }
}

__global__ void crf_mean(const float* __restrict__ pb, float* __restrict__ out) {
  int tid = threadIdx.x;  // 64 threads, one wave
  float v = pb[tid];
  #pragma unroll
  for (int m = 1; m < 64; m <<= 1) v += __shfl_xor(v, m, 64);
  if (tid == 0) out[0] = v * (1.0f / 64.0f);
}

extern "C" void kernel_launch(void* const* d_in, const int* in_sizes, int n_in,
                              void* d_out, int out_size, void* d_ws, size_t ws_size,
                              hipStream_t stream) {
  const float* feats = (const float*)d_in[0];
  const int*   tags  = (const int*)d_in[1];
  const int*   lens  = (const int*)d_in[2];
  const float* trans = (const float*)d_in[3];
  float* pb = (float*)d_ws;   // 64 floats of scratch
  crf_forward<<<BB, NTHREADS, 0, stream>>>(feats, tags, lens, trans, pb);
  crf_mean<<<1, 64, 0, stream>>>(pb, (float*)d_out);
}